// Round 15
// baseline (161.467 us; speedup 1.0000x reference)
//
#include <hip/hip_runtime.h>
#include <cstdint>
#include <cstddef>

#define SEQ 3072
#define DIM 1280
#define NH 16
#define HD 80

typedef __attribute__((ext_vector_type(8))) short s16x8;   // 8 x bf16 (4 VGPR)
typedef __attribute__((ext_vector_type(4))) float f32x4;   // MFMA accumulator
typedef unsigned short u16;
typedef unsigned int u32;
typedef unsigned long long u64;

__device__ __forceinline__ u16 f2bf(float f) {
  u32 u = __builtin_bit_cast(u32, f);
  u32 r = (u + 0x7FFFu + ((u >> 16) & 1u)) >> 16;   // RNE
  return (u16)r;
}
__device__ __forceinline__ float bf2f(u16 b) {
  u32 u = ((u32)b) << 16;
  return __builtin_bit_cast(float, u);
}
__device__ __forceinline__ u32 cvtpk_bf16(float lo, float hi) {
  u32 r;
  asm("v_cvt_pk_bf16_f32 %0, %1, %2" : "=v"(r) : "v"(lo), "v"(hi));
  return r;
}
__device__ __forceinline__ void gload16(const u16* g, u16* lds) {
  __builtin_amdgcn_global_load_lds((const __attribute__((address_space(1))) void*)g,
                                   (__attribute__((address_space(3))) void*)lds,
                                   16, 0, 0);
}

// ---------------- fused f32 -> bf16 convert (hidden, qkv_w, proj_w) ----------------
#define N4_A (SEQ*DIM/4)
#define N4_B (3*DIM*DIM/4)
#define N4_C (DIM*DIM/4)
__global__ void cvt_kernel(const float* __restrict__ sa, u16* __restrict__ da,
                           const float* __restrict__ sb, u16* __restrict__ db,
                           const float* __restrict__ sc, u16* __restrict__ dc) {
  int i = blockIdx.x * blockDim.x + threadIdx.x;
  const float* s; u16* d; int j;
  if (i < N4_A)            { s = sa; d = da; j = i; }
  else if (i < N4_A+N4_B)  { s = sb; d = db; j = i - N4_A; }
  else if (i < N4_A+N4_B+N4_C) { s = sc; d = dc; j = i - N4_A - N4_B; }
  else return;
  float4 v = ((const float4*)s)[j];
  ushort4 o;
  o.x = f2bf(v.x); o.y = f2bf(v.y); o.z = f2bf(v.z); o.w = f2bf(v.w);
  ((ushort4*)d)[j] = o;
}

// ---------------- GEMM: 128x64 tile, 2 waves, BK=32, double-buffered LDS ----
// R14 lesson: gemm0's 128x128 grid (720 blocks = 2.8/CU) was dispatch-limited at
// 28% occupancy; gemm1's 128x64 structure (5.6 blocks/CU, ~12 waves/CU) hits
// ~750 TF vs 437. Both GEMMs now share this shape. Grid: (N/64, M/128).
// MODE 0: qkv scatter (q,k [h][s][80], v^T [h][80][s]); MODE 1: proj f32 out.
template<int MODE>
__global__ __launch_bounds__(128)
void gemm_kernel(const u16* __restrict__ A, const u16* __restrict__ B,
                 const float* __restrict__ bias,
                 u16* __restrict__ qws, u16* __restrict__ kws, u16* __restrict__ vT,
                 float* __restrict__ fout,
                 int M, int N, int K)
{
  constexpr int BM = 128, BN = 64, BK = 32;
  __shared__ __align__(16) u16 As[2][BM*BK];
  __shared__ __align__(16) u16 Bs[2][BN*BK];
  const int m0 = blockIdx.y * BM, n0 = blockIdx.x * BN;
  const int tid = threadIdx.x;
  const int lane = tid & 63, wave = tid >> 6;   // 2 waves stacked on M
  const int lr = lane & 15, lg = lane >> 4;

  int rA[4], cA[4], wbA[4];
  #pragma unroll
  for (int i = 0; i < 4; ++i) {
    const int c = i*128 + tid;
    rA[i] = c >> 2; cA[i] = c & 3;
    wbA[i] = i*128 + (tid & ~63);
  }
  int rB[2], cB[2], wbB[2];
  #pragma unroll
  for (int i = 0; i < 2; ++i) {
    const int c = i*128 + tid;
    rB[i] = c >> 2; cB[i] = c & 3;
    wbB[i] = i*128 + (tid & ~63);
  }

  f32x4 acc[4][4];
  #pragma unroll
  for (int i = 0; i < 4; ++i)
    #pragma unroll
    for (int j = 0; j < 4; ++j) acc[i][j] = (f32x4)0.0f;

  const int NT = K / BK;

  auto stage = [&](int t, int buf) {
    const int k0 = t * BK;
    #pragma unroll
    for (int i = 0; i < 4; ++i)
      gload16(A + (size_t)(m0 + rA[i])*K + k0 + cA[i]*8, &As[buf][0] + wbA[i]*8);
    #pragma unroll
    for (int i = 0; i < 2; ++i)
      gload16(B + (size_t)(n0 + rB[i])*K + k0 + cB[i]*8, &Bs[buf][0] + wbB[i]*8);
  };

  stage(0, 0);
  __syncthreads();

  int cur = 0;
  for (int t = 0; t < NT; ++t) {
    if (t + 1 < NT) stage(t + 1, cur ^ 1);
    s16x8 af[4], bf[4];
    #pragma unroll
    for (int i = 0; i < 4; ++i) {
      af[i] = *(const s16x8*)&As[cur][(wave*64 + i*16 + lr)*BK + lg*8];
      bf[i] = *(const s16x8*)&Bs[cur][(i*16 + lr)*BK + lg*8];
    }
    #pragma unroll
    for (int mi = 0; mi < 4; ++mi)
      #pragma unroll
      for (int ni = 0; ni < 4; ++ni)
        acc[mi][ni] = __builtin_amdgcn_mfma_f32_16x16x32_bf16(af[mi], bf[ni], acc[mi][ni], 0, 0, 0);
    __syncthreads();
    cur ^= 1;
  }

  // epilogue: D layout col = lane&15, row = (lane>>4)*4 + reg
  #pragma unroll
  for (int ni = 0; ni < 4; ++ni) {
    const int n = n0 + ni*16 + lr;
    const float bv = bias[n];
    if constexpr (MODE == 0) {
      const int which = n / DIM;
      const int hd = n - which*DIM;
      const int h = hd / HD;
      const int d = hd - h*HD;
      #pragma unroll
      for (int mi = 0; mi < 4; ++mi) {
        const int mb = m0 + wave*64 + mi*16 + lg*4;
        #pragma unroll
        for (int j = 0; j < 4; ++j) {
          const u16 b = f2bf(acc[mi][ni][j] + bv);
          const int m = mb + j;
          if (which == 0)      qws[((size_t)h*SEQ + m)*HD + d] = b;
          else if (which == 1) kws[((size_t)h*SEQ + m)*HD + d] = b;
          else                 vT [((size_t)h*HD + d)*SEQ + m] = b;
        }
      }
    } else {
      #pragma unroll
      for (int mi = 0; mi < 4; ++mi) {
        const int mb = m0 + wave*64 + mi*16 + lg*4;
        #pragma unroll
        for (int j = 0; j < 4; ++j)
          fout[(size_t)(mb + j)*N + n] = acc[mi][ni][j] + bv;
      }
    }
  }
}

// ---------------- RoPE: cos/sin table, then vectorized apply ----------------
__global__ void rope_tab_kernel(const float* __restrict__ freqs, float2* __restrict__ tab, int n) {
  int i = blockIdx.x*blockDim.x + threadIdx.x;
  if (i >= n) return;
  float f = freqs[i];
  tab[i] = make_float2(cosf(f), sinf(f));
}

__global__ void rope_apply_kernel(u16* __restrict__ q, u16* __restrict__ k,
                                  const float2* __restrict__ tab) {
  int idx = blockIdx.x*blockDim.x + threadIdx.x;   // NH*SEQ*5
  if (idx >= NH*SEQ*5) return;
  const int c = idx % 5;
  const int s = (idx / 5) % SEQ;
  const int h = idx / (5*SEQ);
  const int d0 = c*8;
  const float2* tp = tab + s*(HD/2) + d0;
  float cs[8], sn[8];
  #pragma unroll
  for (int j = 0; j < 8; ++j) { float2 f = tp[j]; cs[j] = f.x; sn[j] = f.y; }
  const size_t base = ((size_t)h*SEQ + s)*HD;
  {
    s16x8 x = *(const s16x8*)(q + base + d0);
    s16x8 y = *(const s16x8*)(q + base + (HD/2) + d0);
    s16x8 nx, ny;
    #pragma unroll
    for (int j = 0; j < 8; ++j) {
      float xv = bf2f((u16)x[j]), yv = bf2f((u16)y[j]);
      nx[j] = (short)f2bf(xv*cs[j] - yv*sn[j]);
      ny[j] = (short)f2bf(yv*cs[j] + xv*sn[j]);
    }
    *(s16x8*)(q + base + d0) = nx;
    *(s16x8*)(q + base + (HD/2) + d0) = ny;
  }
  {
    s16x8 x = *(const s16x8*)(k + base + d0);
    s16x8 y = *(const s16x8*)(k + base + (HD/2) + d0);
    s16x8 nx, ny;
    #pragma unroll
    for (int j = 0; j < 8; ++j) {
      float xv = bf2f((u16)x[j]), yv = bf2f((u16)y[j]);
      nx[j] = (short)f2bf(xv*cs[j] - yv*sn[j]);
      ny[j] = (short)f2bf(yv*cs[j] + xv*sn[j]);
    }
    *(s16x8*)(k + base + d0) = nx;
    *(s16x8*)(k + base + (HD/2) + d0) = ny;
  }
}

// ---------------- attention: split-K x2 (2 indep waves / 32 q rows), end-merge ----
struct AttnState {
  float m_run[2];
  float lp[2];
  f32x4 oacc[2][5];
};

__device__ __forceinline__ void load_kv(const u16* __restrict__ kbase,
                                        const u16* __restrict__ vbase,
                                        int lr, int lg, int kc,
                                        s16x8 (&KF)[2][3], s16x8 (&VF)[5]) {
  int kcl = kc; if (kcl > SEQ-32) kcl = SEQ-32;
  #pragma unroll
  for (int kt = 0; kt < 2; ++kt)
    #pragma unroll
    for (int s = 0; s < 3; ++s) {
      const int d0 = s*32 + lg*8;
      if (d0 < HD) KF[kt][s] = *(const s16x8*)(kbase + (size_t)(kcl + kt*16 + lr)*HD + d0);
      else         KF[kt][s] = (s16x8)(short)0;
    }
  #pragma unroll
  for (int dt = 0; dt < 5; ++dt)
    VF[dt] = *(const s16x8*)(vbase + (size_t)(dt*16 + lr)*SEQ + kcl + lg*8);
}

__device__ __forceinline__ void compute_chunk(int kc, const s16x8 (&KF)[2][3], const s16x8 (&VF)[5],
                                              const s16x8 (&qf)[2][3], AttnState& st,
                                              u16 (&P_lds)[2][16][32],
                                              int lr, int lg, int swz,
                                              int rs0, int re0, int rs1, int re1) {
  const float NEG = -__builtin_inff();
  const float DTH = 8.0f;
  const float kscale = 0.11180339887498949f * 1.44269504088896341f; // 1/sqrt(80)*log2(e)

  f32x4 sacc[2][2];
  #pragma unroll
  for (int qs = 0; qs < 2; ++qs)
    #pragma unroll
    for (int kt = 0; kt < 2; ++kt) sacc[qs][kt] = (f32x4)0.0f;
  #pragma unroll
  for (int kt = 0; kt < 2; ++kt)
    #pragma unroll
    for (int s = 0; s < 3; ++s) {
      sacc[0][kt] = __builtin_amdgcn_mfma_f32_16x16x32_bf16(KF[kt][s], qf[0][s], sacc[0][kt], 0, 0, 0);
      sacc[1][kt] = __builtin_amdgcn_mfma_f32_16x16x32_bf16(KF[kt][s], qf[1][s], sacc[1][kt], 0, 0, 0);
    }

  float sv[2][8];
  #pragma unroll
  for (int qs = 0; qs < 2; ++qs)
    #pragma unroll
    for (int kt = 0; kt < 2; ++kt)
      #pragma unroll
      for (int j = 0; j < 4; ++j)
        sv[qs][kt*4+j] = sacc[qs][kt][j] * kscale;

  const bool full = __all((kc >= rs0) && (kc+32 <= re0) && (kc >= rs1) && (kc+32 <= re1));
  if (!full) {
    #pragma unroll
    for (int qs = 0; qs < 2; ++qs) {
      const int rsq = qs ? rs1 : rs0, req = qs ? re1 : re0;
      #pragma unroll
      for (int kt = 0; kt < 2; ++kt)
        #pragma unroll
        for (int j = 0; j < 4; ++j) {
          const int key = kc + kt*16 + lg*4 + j;
          if (key < rsq || key >= req) sv[qs][kt*4+j] = NEG;
        }
    }
  }

  float pc[2];
  #pragma unroll
  for (int qs = 0; qs < 2; ++qs) {
    float c = sv[qs][0];
    #pragma unroll
    for (int i = 1; i < 8; ++i) c = fmaxf(c, sv[qs][i]);
    pc[qs] = c;
  }

  const bool nore = __all((pc[0] - st.m_run[0] <= DTH) && (pc[1] - st.m_run[1] <= DTH));
  u32 pk[2][4];
  if (nore) {
    #pragma unroll
    for (int qs = 0; qs < 2; ++qs) {
      const float m = st.m_run[qs];
      float ps = 0.0f;
      #pragma unroll
      for (int i2 = 0; i2 < 4; ++i2) {
        float pa = __builtin_amdgcn_exp2f(sv[qs][2*i2]   - m);
        float pb = __builtin_amdgcn_exp2f(sv[qs][2*i2+1] - m);
        ps += pa + pb;
        pk[qs][i2] = cvtpk_bf16(pa, pb);
      }
      st.lp[qs] += ps;
    }
  } else {
    #pragma unroll
    for (int qs = 0; qs < 2; ++qs) {
      float c = pc[qs];
      c = fmaxf(c, __shfl_xor(c, 16, 64));
      c = fmaxf(c, __shfl_xor(c, 32, 64));
      const float mn = fmaxf(st.m_run[qs], c);
      const float fs = (mn == st.m_run[qs]) ? 1.0f : __builtin_amdgcn_exp2f(st.m_run[qs] - mn);
      float ps = 0.0f;
      #pragma unroll
      for (int i2 = 0; i2 < 4; ++i2) {
        float a0 = sv[qs][2*i2], a1 = sv[qs][2*i2+1];
        float pa = (a0 == NEG) ? 0.0f : __builtin_amdgcn_exp2f(a0 - mn);
        float pb = (a1 == NEG) ? 0.0f : __builtin_amdgcn_exp2f(a1 - mn);
        ps += pa + pb;
        pk[qs][i2] = cvtpk_bf16(pa, pb);
      }
      st.lp[qs] = st.lp[qs] * fs + ps;
      st.m_run[qs] = mn;
      float fr[4];
      #pragma unroll
      for (int j = 0; j < 4; ++j)
        fr[j] = __builtin_bit_cast(float,
                  __builtin_amdgcn_ds_bpermute((lg*4 + j)*4, __builtin_bit_cast(int, fs)));
      #pragma unroll
      for (int dt = 0; dt < 5; ++dt)
        #pragma unroll
        for (int j = 0; j < 4; ++j) st.oacc[qs][dt][j] *= fr[j];
    }
  }

  #pragma unroll
  for (int qs = 0; qs < 2; ++qs) {
    u64 w0 = (u64)pk[qs][0] | ((u64)pk[qs][1] << 32);
    u64 w1 = (u64)pk[qs][2] | ((u64)pk[qs][3] << 32);
    u64* P64 = (u64*)&P_lds[qs][0][0];
    P64[lr*8 + ( lg      ^ (swz<<1))] = w0;
    P64[lr*8 + ((4 + lg) ^ (swz<<1))] = w1;
  }
  s16x8 pa0 = *(const s16x8*)&P_lds[0][lr][(lg ^ swz) * 8];
  s16x8 pa1 = *(const s16x8*)&P_lds[1][lr][(lg ^ swz) * 8];

  #pragma unroll
  for (int dt = 0; dt < 5; ++dt) {
    st.oacc[0][dt] = __builtin_amdgcn_mfma_f32_16x16x32_bf16(pa0, VF[dt], st.oacc[0][dt], 0, 0, 0);
    st.oacc[1][dt] = __builtin_amdgcn_mfma_f32_16x16x32_bf16(pa1, VF[dt], st.oacc[1][dt], 0, 0, 0);
  }
}

__global__ __launch_bounds__(128)
void attn_kernel(const u16* __restrict__ qws, const u16* __restrict__ kws,
                 const u16* __restrict__ vT, const int* __restrict__ cu, int ncu,
                 u16* __restrict__ ows /* [SEQ][DIM] bf16 */)
{
  __shared__ __align__(16) u16 P_lds[2][2][16][32];   // [wave][qs][q][32 keys]
  __shared__ float mstat[2][2][16];                   // [wave][qs][row(lr)]
  __shared__ float lstat[2][2][16];
  __shared__ float O_lds[32][84];                     // wave1's scaled O (+4 pad)
  const int h = blockIdx.x & 15;         // head pinned by bid%8 == h%8
  const int t = blockIdx.x >> 4;
  const int tid = threadIdx.x;
  const int w = tid >> 6;
  const int lane = tid & 63;
  const int lr = lane & 15, lg = lane >> 4;
  const int q0 = t*32;
  const float NEG = -__builtin_inff();

  int rs0 = cu[0], re0 = cu[1], rs1 = cu[0], re1 = cu[1];
  int ts = cu[0], te = cu[1];
  {
    const int qa = q0 + lr, qb = q0 + 16 + lr;
    for (int i = 1; i < ncu-1; ++i) {
      int lo = cu[i], hi = cu[i+1];
      if (qa    >= lo) { rs0 = lo; re0 = hi; }
      if (qb    >= lo) { rs1 = lo; re1 = hi; }
      if (q0    >= lo) { ts = lo; }
      if (q0+31 >= lo) { te = hi; }
    }
  }

  const u16* kbase = kws + (size_t)h*SEQ*HD;
  const u16* vbase = vT  + (size_t)h*HD*SEQ;

  s16x8 qf[2][3];
  #pragma unroll
  for (int qs = 0; qs < 2; ++qs)
    #pragma unroll
    for (int s = 0; s < 3; ++s) {
      int d0 = s*32 + lg*8;
      if (d0 < HD) qf[qs][s] = *(const s16x8*)(qws + ((size_t)h*SEQ + q0 + qs*16 + lr)*HD + d0);
      else         qf[qs][s] = (s16x8)(short)0;
    }

  AttnState st;
  st.m_run[0] = NEG; st.m_run[1] = NEG;
  st.lp[0] = 0.0f;   st.lp[1] = 0.0f;
  #pragma unroll
  for (int qs = 0; qs < 2; ++qs)
    #pragma unroll
    for (int dt = 0; dt < 5; ++dt) st.oacc[qs][dt] = (f32x4)0.0f;

  const int swz = (lr >> 1) & 3;

  const int kc0 = ts & ~31;
  const int nch = (te - kc0 + 31) >> 5;
  const int n_w = (nch - w + 1) >> 1;    // chunks at indices w, w+2, ...

  s16x8 kfA[2][3], vfA[5], kfB[2][3], vfB[5];
  const int kcw0 = kc0 + w*32;
  if (n_w > 0) load_kv(kbase, vbase, lr, lg, kcw0, kfA, vfA);

  int kc = kcw0, i = 0;
  for (; i + 2 <= n_w; i += 2) {
    load_kv(kbase, vbase, lr, lg, kc+64,  kfB, vfB);    // prefetch n+1 (stride 64)
    compute_chunk(kc, kfA, vfA, qf, st, P_lds[w], lr, lg, swz, rs0, re0, rs1, re1);
    load_kv(kbase, vbase, lr, lg, kc+128, kfA, vfA);    // prefetch n+2 (clamped)
    compute_chunk(kc+64, kfB, vfB, qf, st, P_lds[w], lr, lg, swz, rs0, re0, rs1, re1);
    kc += 128;
  }
  if (i < n_w)
    compute_chunk(kc, kfA, vfA, qf, st, P_lds[w], lr, lg, swz, rs0, re0, rs1, re1);

  // ---- finalize per-wave l; publish (m, l) per row ----
  #pragma unroll
  for (int qs = 0; qs < 2; ++qs) {
    st.lp[qs] += __shfl_xor(st.lp[qs], 16, 64);
    st.lp[qs] += __shfl_xor(st.lp[qs], 32, 64);
  }
  if (lg == 0) {
    mstat[w][0][lr] = st.m_run[0]; lstat[w][0][lr] = st.lp[0];
    mstat[w][1][lr] = st.m_run[1]; lstat[w][1][lr] = st.lp[1];
  }
  __syncthreads();

  // ---- per-lane merge factors for own rows r = lg*4+j ----
  float fac[2][4], lin[2][4];
  #pragma unroll
  for (int qs = 0; qs < 2; ++qs)
    #pragma unroll
    for (int j = 0; j < 4; ++j) {
      const int r = lg*4 + j;
      const float m0 = mstat[0][qs][r], m1 = mstat[1][qs][r];
      const float mst = fmaxf(m0, m1);
      float lst = 0.0f;
      if (m0 != NEG) lst += lstat[0][qs][r] * __builtin_amdgcn_exp2f(m0 - mst);
      if (m1 != NEG) lst += lstat[1][qs][r] * __builtin_amdgcn_exp2f(m1 - mst);
      const float mw = w ? m1 : m0;
      fac[qs][j] = (mw == NEG) ? 0.0f : __builtin_amdgcn_exp2f(mw - mst);
      lin[qs][j] = 1.0f / lst;
    }

  // ---- wave 1 deposits scaled O; wave 0 combines, normalizes, stores ----
  if (w == 1) {
    #pragma unroll
    for (int qs = 0; qs < 2; ++qs)
      #pragma unroll
      for (int dt = 0; dt < 5; ++dt)
        #pragma unroll
        for (int j = 0; j < 4; ++j)
          O_lds[qs*16 + lg*4 + j][dt*16 + lr] = st.oacc[qs][dt][j] * fac[qs][j];
  }
  __syncthreads();
  if (w == 0) {
    #pragma unroll
    for (int qs = 0; qs < 2; ++qs)
      #pragma unroll
      for (int dt = 0; dt < 5; ++dt)
        #pragma unroll
        for (int j = 0; j < 4; ++j) {
          float v = (st.oacc[qs][dt][j] * fac[qs][j] + O_lds[qs*16 + lg*4 + j][dt*16 + lr])
                    * lin[qs][j];
          ows[(size_t)(q0 + qs*16 + lg*4 + j)*DIM + h*HD + dt*16 + lr] = f2bf(v);
        }
  }
}

// ---------------- launch ----------------
extern "C" void kernel_launch(void* const* d_in, const int* in_sizes, int n_in,
                              void* d_out, int out_size, void* d_ws, size_t ws_size,
                              hipStream_t stream) {
  const float* hidden = (const float*)d_in[0];
  const float* rope   = (const float*)d_in[1];
  const int*   cu     = (const int*)d_in[2];
  const float* qkv_w  = (const float*)d_in[3];
  const float* qkv_b  = (const float*)d_in[4];
  const float* proj_w = (const float*)d_in[5];
  const float* proj_b = (const float*)d_in[6];
  float* out = (float*)d_out;
  const int ncu = in_sizes[2];

  // workspace layout (~52.4 MB total)
  char* ws = (char*)d_ws;
  u16* Abf = (u16*)ws; ws += (size_t)SEQ*DIM*2;       // hidden bf16 (reused as rope table after gemm0)
  u16* Wq  = (u16*)ws; ws += (size_t)3*DIM*DIM*2;     // qkv_w bf16
  u16* Wp  = (u16*)ws; ws += (size_t)DIM*DIM*2;       // proj_w bf16
  u16* qws = (u16*)ws; ws += (size_t)NH*SEQ*HD*2;     // q [h][s][80]
  u16* kws = (u16*)ws; ws += (size_t)NH*SEQ*HD*2;     // k [h][s][80]
  u16* vTw = (u16*)ws; ws += (size_t)NH*SEQ*HD*2;     // v^T [h][80][s]
  u16* ows = (u16*)ws; ws += (size_t)SEQ*DIM*2;       // attn out [s][1280]

  cvt_kernel<<<(N4_A+N4_B+N4_C+255)/256, 256, 0, stream>>>(hidden, Abf, qkv_w, Wq, proj_w, Wp);

  gemm_kernel<0><<<dim3(3*DIM/64, SEQ/128), 128, 0, stream>>>(
      Abf, Wq, qkv_b, qws, kws, vTw, nullptr, SEQ, 3*DIM, DIM);

  // rope table overwrites Abf (dead after gemm0)
  float2* tab = (float2*)Abf;
  rope_tab_kernel<<<(SEQ*(HD/2) + 255)/256, 256, 0, stream>>>(rope, tab, SEQ*(HD/2));
  rope_apply_kernel<<<(NH*SEQ*5 + 255)/256, 256, 0, stream>>>(qws, kws, tab);

  attn_kernel<<<NH*(SEQ/32), 128, 0, stream>>>(qws, kws, vTw, cu, ncu, ows);

  gemm_kernel<1><<<dim3(DIM/64, SEQ/128), 128, 0, stream>>>(
      ows, Wp, proj_b, nullptr, nullptr, nullptr, out, SEQ, DIM, DIM);
}

// Round 16
// 153.627 us; speedup vs baseline: 1.0510x; 1.0510x over previous
//
#include <hip/hip_runtime.h>
#include <cstdint>
#include <cstddef>

#define SEQ 3072
#define DIM 1280
#define NH 16
#define HD 80

typedef __attribute__((ext_vector_type(8))) short s16x8;   // 8 x bf16 (4 VGPR)
typedef __attribute__((ext_vector_type(4))) float f32x4;   // MFMA accumulator
typedef unsigned short u16;
typedef unsigned int u32;
typedef unsigned long long u64;

__device__ __forceinline__ u16 f2bf(float f) {
  u32 u = __builtin_bit_cast(u32, f);
  u32 r = (u + 0x7FFFu + ((u >> 16) & 1u)) >> 16;   // RNE
  return (u16)r;
}
__device__ __forceinline__ float bf2f(u16 b) {
  u32 u = ((u32)b) << 16;
  return __builtin_bit_cast(float, u);
}
__device__ __forceinline__ u32 cvtpk_bf16(float lo, float hi) {
  u32 r;
  asm("v_cvt_pk_bf16_f32 %0, %1, %2" : "=v"(r) : "v"(lo), "v"(hi));
  return r;
}
__device__ __forceinline__ void gload16(const u16* g, u16* lds) {
  __builtin_amdgcn_global_load_lds((const __attribute__((address_space(1))) void*)g,
                                   (__attribute__((address_space(3))) void*)lds,
                                   16, 0, 0);
}

// ---------------- fused f32->bf16 convert (hidden, qkv_w, proj_w) + rope table ----
#define N4_A (SEQ*DIM/4)
#define N4_B (3*DIM*DIM/4)
#define N4_C (DIM*DIM/4)
#define NTAB (SEQ*(HD/2))
__global__ void cvt_kernel(const float* __restrict__ sa, u16* __restrict__ da,
                           const float* __restrict__ sb, u16* __restrict__ db,
                           const float* __restrict__ sc, u16* __restrict__ dc,
                           const float* __restrict__ freqs, float2* __restrict__ tab) {
  int i = blockIdx.x * blockDim.x + threadIdx.x;
  if (i < N4_A + N4_B + N4_C) {
    const float* s; u16* d; int j;
    if (i < N4_A)           { s = sa; d = da; j = i; }
    else if (i < N4_A+N4_B) { s = sb; d = db; j = i - N4_A; }
    else                    { s = sc; d = dc; j = i - N4_A - N4_B; }
    float4 v = ((const float4*)s)[j];
    ushort4 o;
    o.x = f2bf(v.x); o.y = f2bf(v.y); o.z = f2bf(v.z); o.w = f2bf(v.w);
    ((ushort4*)d)[j] = o;
  } else {
    int j = i - (N4_A + N4_B + N4_C);
    if (j < NTAB) {
      float f = freqs[j];
      tab[j] = make_float2(cosf(f), sinf(f));
    }
  }
}

// ---------------- qkv GEMM: 128x128, BK=32, dbuf, COUNTED vmcnt (T4, no pins) ----
// R8's counted-vmcnt regressed WITH sched_barrier(0) pins (m141 mechanism);
// retried here pin-free: "memory" clobber on the waits orders all LDS/VMEM ops,
// and MFMA data-deps prevent hoisting. Tile t+1's 4 loads stay in flight across
// the top barrier (vmcnt(4)); stage t+2 after the bottom barrier.
__global__ __launch_bounds__(256)
void gemm_kernel(const u16* __restrict__ A, const u16* __restrict__ B,
                 const float* __restrict__ bias,
                 u16* __restrict__ qws, u16* __restrict__ kws, u16* __restrict__ vT,
                 int M, int N, int K)
{
  constexpr int BM = 128, BN = 128, BK = 32;
  __shared__ __align__(16) u16 As[2][BM*BK];
  __shared__ __align__(16) u16 Bs[2][BN*BK];
  const int m0 = blockIdx.y * BM, n0 = blockIdx.x * BN;
  const int tid = threadIdx.x;
  const int lane = tid & 63, wave = tid >> 6;
  const int wr = wave >> 1, wc = wave & 1;     // 2x2 waves, each 64x64
  const int lr = lane & 15, lg = lane >> 4;

  const int c0 = tid, c1 = 256 + tid;
  const int r0 = c0 >> 2, cc0 = c0 & 3;
  const int r1 = c1 >> 2, cc1 = c1 & 3;
  const int wb0 = (tid & ~63), wb1 = 256 + (tid & ~63);

  auto stage = [&](int t, int buf) {
    const int k0 = t * BK;
    gload16(A + (size_t)(m0 + r0)*K + k0 + cc0*8, &As[buf][0] + wb0*8);
    gload16(B + (size_t)(n0 + r0)*K + k0 + cc0*8, &Bs[buf][0] + wb0*8);
    gload16(A + (size_t)(m0 + r1)*K + k0 + cc1*8, &As[buf][0] + wb1*8);
    gload16(B + (size_t)(n0 + r1)*K + k0 + cc1*8, &Bs[buf][0] + wb1*8);
  };

  f32x4 acc[4][4];
  #pragma unroll
  for (int i = 0; i < 4; ++i)
    #pragma unroll
    for (int j = 0; j < 4; ++j) acc[i][j] = (f32x4)0.0f;

  const int NT = K / BK;   // 40

  stage(0, 0);   // 4 loads in flight
  stage(1, 1);   // 8 in flight

  int cur = 0;
  for (int t = 0; t < NT; ++t) {
    // wait only for tile t's 4 loads; tile t+1's stay in flight across the barrier
    if (t == NT - 1) asm volatile("s_waitcnt vmcnt(0)" ::: "memory");
    else             asm volatile("s_waitcnt vmcnt(4)" ::: "memory");
    __builtin_amdgcn_s_barrier();

    s16x8 af[4], bf[4];
    #pragma unroll
    for (int i = 0; i < 4; ++i) {
      af[i] = *(const s16x8*)&As[cur][(wr*64 + i*16 + lr)*BK + lg*8];
      bf[i] = *(const s16x8*)&Bs[cur][(wc*64 + i*16 + lr)*BK + lg*8];
    }
    #pragma unroll
    for (int mi = 0; mi < 4; ++mi)
      #pragma unroll
      for (int ni = 0; ni < 4; ++ni)
        acc[mi][ni] = __builtin_amdgcn_mfma_f32_16x16x32_bf16(af[mi], bf[ni], acc[mi][ni], 0, 0, 0);

    // this wave's ds_reads complete before any wave overwrites buf cur
    asm volatile("s_waitcnt lgkmcnt(0)" ::: "memory");
    __builtin_amdgcn_s_barrier();

    if (t + 2 < NT) stage(t + 2, cur);   // into the just-consumed buffer
    cur ^= 1;
  }

  // epilogue: D layout col = lane&15, row = (lane>>4)*4 + reg; scatter q,k,v^T
  #pragma unroll
  for (int ni = 0; ni < 4; ++ni) {
    const int n = n0 + wc*64 + ni*16 + lr;
    const float bv = bias[n];
    const int which = n / DIM;
    const int hd = n - which*DIM;
    const int h = hd / HD;
    const int d = hd - h*HD;
    #pragma unroll
    for (int mi = 0; mi < 4; ++mi) {
      const int mb = m0 + wr*64 + mi*16 + lg*4;
      #pragma unroll
      for (int j = 0; j < 4; ++j) {
        const u16 b = f2bf(acc[mi][ni][j] + bv);
        const int m = mb + j;
        if (which == 0)      qws[((size_t)h*SEQ + m)*HD + d] = b;
        else if (which == 1) kws[((size_t)h*SEQ + m)*HD + d] = b;
        else                 vT [((size_t)h*HD + d)*SEQ + m] = b;
      }
    }
  }
}

// ---------------- proj GEMM: 128x64 tile, 2 waves, dbuf (grid 480) ----
__global__ __launch_bounds__(128)
void gemm1_kernel(const u16* __restrict__ A, const u16* __restrict__ B,
                  const float* __restrict__ bias, float* __restrict__ fout,
                  int M, int N, int K)
{
  constexpr int BM = 128, BN = 64, BK = 32;
  __shared__ __align__(16) u16 As[2][BM*BK];
  __shared__ __align__(16) u16 Bs[2][BN*BK];
  const int m0 = blockIdx.y * BM, n0 = blockIdx.x * BN;
  const int tid = threadIdx.x;
  const int lane = tid & 63, wave = tid >> 6;   // 2 waves stacked on M
  const int lr = lane & 15, lg = lane >> 4;

  int rA[4], cA[4], wbA[4];
  #pragma unroll
  for (int i = 0; i < 4; ++i) {
    const int c = i*128 + tid;
    rA[i] = c >> 2; cA[i] = c & 3;
    wbA[i] = i*128 + (tid & ~63);
  }
  int rB[2], cB[2], wbB[2];
  #pragma unroll
  for (int i = 0; i < 2; ++i) {
    const int c = i*128 + tid;
    rB[i] = c >> 2; cB[i] = c & 3;
    wbB[i] = i*128 + (tid & ~63);
  }

  f32x4 acc[4][4];
  #pragma unroll
  for (int i = 0; i < 4; ++i)
    #pragma unroll
    for (int j = 0; j < 4; ++j) acc[i][j] = (f32x4)0.0f;

  const int NT = K / BK;

  auto stage = [&](int t, int buf) {
    const int k0 = t * BK;
    #pragma unroll
    for (int i = 0; i < 4; ++i)
      gload16(A + (size_t)(m0 + rA[i])*K + k0 + cA[i]*8, &As[buf][0] + wbA[i]*8);
    #pragma unroll
    for (int i = 0; i < 2; ++i)
      gload16(B + (size_t)(n0 + rB[i])*K + k0 + cB[i]*8, &Bs[buf][0] + wbB[i]*8);
  };

  stage(0, 0);
  __syncthreads();

  int cur = 0;
  for (int t = 0; t < NT; ++t) {
    if (t + 1 < NT) stage(t + 1, cur ^ 1);
    s16x8 af[4], bf[4];
    #pragma unroll
    for (int i = 0; i < 4; ++i) {
      af[i] = *(const s16x8*)&As[cur][(wave*64 + i*16 + lr)*BK + lg*8];
      bf[i] = *(const s16x8*)&Bs[cur][(i*16 + lr)*BK + lg*8];
    }
    #pragma unroll
    for (int mi = 0; mi < 4; ++mi)
      #pragma unroll
      for (int ni = 0; ni < 4; ++ni)
        acc[mi][ni] = __builtin_amdgcn_mfma_f32_16x16x32_bf16(af[mi], bf[ni], acc[mi][ni], 0, 0, 0);
    __syncthreads();
    cur ^= 1;
  }

  #pragma unroll
  for (int ni = 0; ni < 4; ++ni) {
    const int n = n0 + ni*16 + lr;
    const float bv = bias[n];
    #pragma unroll
    for (int mi = 0; mi < 4; ++mi) {
      const int mb = m0 + wave*64 + mi*16 + lg*4;
      #pragma unroll
      for (int j = 0; j < 4; ++j)
        fout[(size_t)(mb + j)*N + n] = acc[mi][ni][j] + bv;
    }
  }
}

// ---------------- RoPE apply (vectorized; tab precomputed in cvt) ----------------
__global__ void rope_apply_kernel(u16* __restrict__ q, u16* __restrict__ k,
                                  const float2* __restrict__ tab) {
  int idx = blockIdx.x*blockDim.x + threadIdx.x;   // NH*SEQ*5
  if (idx >= NH*SEQ*5) return;
  const int c = idx % 5;
  const int s = (idx / 5) % SEQ;
  const int h = idx / (5*SEQ);
  const int d0 = c*8;
  const float2* tp = tab + s*(HD/2) + d0;
  float cs[8], sn[8];
  #pragma unroll
  for (int j = 0; j < 8; ++j) { float2 f = tp[j]; cs[j] = f.x; sn[j] = f.y; }
  const size_t base = ((size_t)h*SEQ + s)*HD;
  {
    s16x8 x = *(const s16x8*)(q + base + d0);
    s16x8 y = *(const s16x8*)(q + base + (HD/2) + d0);
    s16x8 nx, ny;
    #pragma unroll
    for (int j = 0; j < 8; ++j) {
      float xv = bf2f((u16)x[j]), yv = bf2f((u16)y[j]);
      nx[j] = (short)f2bf(xv*cs[j] - yv*sn[j]);
      ny[j] = (short)f2bf(yv*cs[j] + xv*sn[j]);
    }
    *(s16x8*)(q + base + d0) = nx;
    *(s16x8*)(q + base + (HD/2) + d0) = ny;
  }
  {
    s16x8 x = *(const s16x8*)(k + base + d0);
    s16x8 y = *(const s16x8*)(k + base + (HD/2) + d0);
    s16x8 nx, ny;
    #pragma unroll
    for (int j = 0; j < 8; ++j) {
      float xv = bf2f((u16)x[j]), yv = bf2f((u16)y[j]);
      nx[j] = (short)f2bf(xv*cs[j] - yv*sn[j]);
      ny[j] = (short)f2bf(yv*cs[j] + xv*sn[j]);
    }
    *(s16x8*)(k + base + d0) = nx;
    *(s16x8*)(k + base + (HD/2) + d0) = ny;
  }
}

// ---------------- attention: split-K x2 (2 indep waves / 32 q rows), end-merge ----
struct AttnState {
  float m_run[2];
  float lp[2];
  f32x4 oacc[2][5];
};

__device__ __forceinline__ void load_kv(const u16* __restrict__ kbase,
                                        const u16* __restrict__ vbase,
                                        int lr, int lg, int kc,
                                        s16x8 (&KF)[2][3], s16x8 (&VF)[5]) {
  int kcl = kc; if (kcl > SEQ-32) kcl = SEQ-32;
  #pragma unroll
  for (int kt = 0; kt < 2; ++kt)
    #pragma unroll
    for (int s = 0; s < 3; ++s) {
      const int d0 = s*32 + lg*8;
      if (d0 < HD) KF[kt][s] = *(const s16x8*)(kbase + (size_t)(kcl + kt*16 + lr)*HD + d0);
      else         KF[kt][s] = (s16x8)(short)0;
    }
  #pragma unroll
  for (int dt = 0; dt < 5; ++dt)
    VF[dt] = *(const s16x8*)(vbase + (size_t)(dt*16 + lr)*SEQ + kcl + lg*8);
}

__device__ __forceinline__ void compute_chunk(int kc, const s16x8 (&KF)[2][3], const s16x8 (&VF)[5],
                                              const s16x8 (&qf)[2][3], AttnState& st,
                                              u16 (&P_lds)[2][16][32],
                                              int lr, int lg, int swz,
                                              int rs0, int re0, int rs1, int re1) {
  const float NEG = -__builtin_inff();
  const float DTH = 8.0f;
  const float kscale = 0.11180339887498949f * 1.44269504088896341f; // 1/sqrt(80)*log2(e)

  f32x4 sacc[2][2];
  #pragma unroll
  for (int qs = 0; qs < 2; ++qs)
    #pragma unroll
    for (int kt = 0; kt < 2; ++kt) sacc[qs][kt] = (f32x4)0.0f;
  #pragma unroll
  for (int kt = 0; kt < 2; ++kt)
    #pragma unroll
    for (int s = 0; s < 3; ++s) {
      sacc[0][kt] = __builtin_amdgcn_mfma_f32_16x16x32_bf16(KF[kt][s], qf[0][s], sacc[0][kt], 0, 0, 0);
      sacc[1][kt] = __builtin_amdgcn_mfma_f32_16x16x32_bf16(KF[kt][s], qf[1][s], sacc[1][kt], 0, 0, 0);
    }

  float sv[2][8];
  #pragma unroll
  for (int qs = 0; qs < 2; ++qs)
    #pragma unroll
    for (int kt = 0; kt < 2; ++kt)
      #pragma unroll
      for (int j = 0; j < 4; ++j)
        sv[qs][kt*4+j] = sacc[qs][kt][j] * kscale;

  const bool full = __all((kc >= rs0) && (kc+32 <= re0) && (kc >= rs1) && (kc+32 <= re1));
  if (!full) {
    #pragma unroll
    for (int qs = 0; qs < 2; ++qs) {
      const int rsq = qs ? rs1 : rs0, req = qs ? re1 : re0;
      #pragma unroll
      for (int kt = 0; kt < 2; ++kt)
        #pragma unroll
        for (int j = 0; j < 4; ++j) {
          const int key = kc + kt*16 + lg*4 + j;
          if (key < rsq || key >= req) sv[qs][kt*4+j] = NEG;
        }
    }
  }

  float pc[2];
  #pragma unroll
  for (int qs = 0; qs < 2; ++qs) {
    float c = sv[qs][0];
    #pragma unroll
    for (int i = 1; i < 8; ++i) c = fmaxf(c, sv[qs][i]);
    pc[qs] = c;
  }

  const bool nore = __all((pc[0] - st.m_run[0] <= DTH) && (pc[1] - st.m_run[1] <= DTH));
  u32 pk[2][4];
  if (nore) {
    #pragma unroll
    for (int qs = 0; qs < 2; ++qs) {
      const float m = st.m_run[qs];
      float ps = 0.0f;
      #pragma unroll
      for (int i2 = 0; i2 < 4; ++i2) {
        float pa = __builtin_amdgcn_exp2f(sv[qs][2*i2]   - m);
        float pb = __builtin_amdgcn_exp2f(sv[qs][2*i2+1] - m);
        ps += pa + pb;
        pk[qs][i2] = cvtpk_bf16(pa, pb);
      }
      st.lp[qs] += ps;
    }
  } else {
    #pragma unroll
    for (int qs = 0; qs < 2; ++qs) {
      float c = pc[qs];
      c = fmaxf(c, __shfl_xor(c, 16, 64));
      c = fmaxf(c, __shfl_xor(c, 32, 64));
      const float mn = fmaxf(st.m_run[qs], c);
      const float fs = (mn == st.m_run[qs]) ? 1.0f : __builtin_amdgcn_exp2f(st.m_run[qs] - mn);
      float ps = 0.0f;
      #pragma unroll
      for (int i2 = 0; i2 < 4; ++i2) {
        float a0 = sv[qs][2*i2], a1 = sv[qs][2*i2+1];
        float pa = (a0 == NEG) ? 0.0f : __builtin_amdgcn_exp2f(a0 - mn);
        float pb = (a1 == NEG) ? 0.0f : __builtin_amdgcn_exp2f(a1 - mn);
        ps += pa + pb;
        pk[qs][i2] = cvtpk_bf16(pa, pb);
      }
      st.lp[qs] = st.lp[qs] * fs + ps;
      st.m_run[qs] = mn;
      float fr[4];
      #pragma unroll
      for (int j = 0; j < 4; ++j)
        fr[j] = __builtin_bit_cast(float,
                  __builtin_amdgcn_ds_bpermute((lg*4 + j)*4, __builtin_bit_cast(int, fs)));
      #pragma unroll
      for (int dt = 0; dt < 5; ++dt)
        #pragma unroll
        for (int j = 0; j < 4; ++j) st.oacc[qs][dt][j] *= fr[j];
    }
  }

  #pragma unroll
  for (int qs = 0; qs < 2; ++qs) {
    u64 w0 = (u64)pk[qs][0] | ((u64)pk[qs][1] << 32);
    u64 w1 = (u64)pk[qs][2] | ((u64)pk[qs][3] << 32);
    u64* P64 = (u64*)&P_lds[qs][0][0];
    P64[lr*8 + ( lg      ^ (swz<<1))] = w0;
    P64[lr*8 + ((4 + lg) ^ (swz<<1))] = w1;
  }
  s16x8 pa0 = *(const s16x8*)&P_lds[0][lr][(lg ^ swz) * 8];
  s16x8 pa1 = *(const s16x8*)&P_lds[1][lr][(lg ^ swz) * 8];

  #pragma unroll
  for (int dt = 0; dt < 5; ++dt) {
    st.oacc[0][dt] = __builtin_amdgcn_mfma_f32_16x16x32_bf16(pa0, VF[dt], st.oacc[0][dt], 0, 0, 0);
    st.oacc[1][dt] = __builtin_amdgcn_mfma_f32_16x16x32_bf16(pa1, VF[dt], st.oacc[1][dt], 0, 0, 0);
  }
}

__global__ __launch_bounds__(128)
void attn_kernel(const u16* __restrict__ qws, const u16* __restrict__ kws,
                 const u16* __restrict__ vT, const int* __restrict__ cu, int ncu,
                 u16* __restrict__ ows /* [SEQ][DIM] bf16 */)
{
  __shared__ __align__(16) u16 P_lds[2][2][16][32];   // [wave][qs][q][32 keys]
  __shared__ float mstat[2][2][16];                   // [wave][qs][row(lr)]
  __shared__ float lstat[2][2][16];
  __shared__ float O_lds[32][84];                     // wave1's scaled O (+4 pad)
  const int h = blockIdx.x & 15;         // head pinned by bid%8 == h%8
  const int t = blockIdx.x >> 4;
  const int tid = threadIdx.x;
  const int w = tid >> 6;
  const int lane = tid & 63;
  const int lr = lane & 15, lg = lane >> 4;
  const int q0 = t*32;
  const float NEG = -__builtin_inff();

  int rs0 = cu[0], re0 = cu[1], rs1 = cu[0], re1 = cu[1];
  int ts = cu[0], te = cu[1];
  {
    const int qa = q0 + lr, qb = q0 + 16 + lr;
    for (int i = 1; i < ncu-1; ++i) {
      int lo = cu[i], hi = cu[i+1];
      if (qa    >= lo) { rs0 = lo; re0 = hi; }
      if (qb    >= lo) { rs1 = lo; re1 = hi; }
      if (q0    >= lo) { ts = lo; }
      if (q0+31 >= lo) { te = hi; }
    }
  }

  const u16* kbase = kws + (size_t)h*SEQ*HD;
  const u16* vbase = vT  + (size_t)h*HD*SEQ;

  s16x8 qf[2][3];
  #pragma unroll
  for (int qs = 0; qs < 2; ++qs)
    #pragma unroll
    for (int s = 0; s < 3; ++s) {
      int d0 = s*32 + lg*8;
      if (d0 < HD) qf[qs][s] = *(const s16x8*)(qws + ((size_t)h*SEQ + q0 + qs*16 + lr)*HD + d0);
      else         qf[qs][s] = (s16x8)(short)0;
    }

  AttnState st;
  st.m_run[0] = NEG; st.m_run[1] = NEG;
  st.lp[0] = 0.0f;   st.lp[1] = 0.0f;
  #pragma unroll
  for (int qs = 0; qs < 2; ++qs)
    #pragma unroll
    for (int dt = 0; dt < 5; ++dt) st.oacc[qs][dt] = (f32x4)0.0f;

  const int swz = (lr >> 1) & 3;

  const int kc0 = ts & ~31;
  const int nch = (te - kc0 + 31) >> 5;
  const int n_w = (nch - w + 1) >> 1;    // chunks at indices w, w+2, ...

  s16x8 kfA[2][3], vfA[5], kfB[2][3], vfB[5];
  const int kcw0 = kc0 + w*32;
  if (n_w > 0) load_kv(kbase, vbase, lr, lg, kcw0, kfA, vfA);

  int kc = kcw0, i = 0;
  for (; i + 2 <= n_w; i += 2) {
    load_kv(kbase, vbase, lr, lg, kc+64,  kfB, vfB);    // prefetch n+1 (stride 64)
    compute_chunk(kc, kfA, vfA, qf, st, P_lds[w], lr, lg, swz, rs0, re0, rs1, re1);
    load_kv(kbase, vbase, lr, lg, kc+128, kfA, vfA);    // prefetch n+2 (clamped)
    compute_chunk(kc+64, kfB, vfB, qf, st, P_lds[w], lr, lg, swz, rs0, re0, rs1, re1);
    kc += 128;
  }
  if (i < n_w)
    compute_chunk(kc, kfA, vfA, qf, st, P_lds[w], lr, lg, swz, rs0, re0, rs1, re1);

  // ---- finalize per-wave l; publish (m, l) per row ----
  #pragma unroll
  for (int qs = 0; qs < 2; ++qs) {
    st.lp[qs] += __shfl_xor(st.lp[qs], 16, 64);
    st.lp[qs] += __shfl_xor(st.lp[qs], 32, 64);
  }
  if (lg == 0) {
    mstat[w][0][lr] = st.m_run[0]; lstat[w][0][lr] = st.lp[0];
    mstat[w][1][lr] = st.m_run[1]; lstat[w][1][lr] = st.lp[1];
  }
  __syncthreads();

  // ---- per-lane merge factors for own rows r = lg*4+j ----
  float fac[2][4], lin[2][4];
  #pragma unroll
  for (int qs = 0; qs < 2; ++qs)
    #pragma unroll
    for (int j = 0; j < 4; ++j) {
      const int r = lg*4 + j;
      const float m0 = mstat[0][qs][r], m1 = mstat[1][qs][r];
      const float mst = fmaxf(m0, m1);
      float lst = 0.0f;
      if (m0 != NEG) lst += lstat[0][qs][r] * __builtin_amdgcn_exp2f(m0 - mst);
      if (m1 != NEG) lst += lstat[1][qs][r] * __builtin_amdgcn_exp2f(m1 - mst);
      const float mw = w ? m1 : m0;
      fac[qs][j] = (mw == NEG) ? 0.0f : __builtin_amdgcn_exp2f(mw - mst);
      lin[qs][j] = 1.0f / lst;
    }

  // ---- wave 1 deposits scaled O; wave 0 combines, normalizes, stores ----
  if (w == 1) {
    #pragma unroll
    for (int qs = 0; qs < 2; ++qs)
      #pragma unroll
      for (int dt = 0; dt < 5; ++dt)
        #pragma unroll
        for (int j = 0; j < 4; ++j)
          O_lds[qs*16 + lg*4 + j][dt*16 + lr] = st.oacc[qs][dt][j] * fac[qs][j];
  }
  __syncthreads();
  if (w == 0) {
    #pragma unroll
    for (int qs = 0; qs < 2; ++qs)
      #pragma unroll
      for (int dt = 0; dt < 5; ++dt)
        #pragma unroll
        for (int j = 0; j < 4; ++j) {
          float v = (st.oacc[qs][dt][j] * fac[qs][j] + O_lds[qs*16 + lg*4 + j][dt*16 + lr])
                    * lin[qs][j];
          ows[(size_t)(q0 + qs*16 + lg*4 + j)*DIM + h*HD + dt*16 + lr] = f2bf(v);
        }
  }
}

// ---------------- launch ----------------
extern "C" void kernel_launch(void* const* d_in, const int* in_sizes, int n_in,
                              void* d_out, int out_size, void* d_ws, size_t ws_size,
                              hipStream_t stream) {
  const float* hidden = (const float*)d_in[0];
  const float* rope   = (const float*)d_in[1];
  const int*   cu     = (const int*)d_in[2];
  const float* qkv_w  = (const float*)d_in[3];
  const float* qkv_b  = (const float*)d_in[4];
  const float* proj_w = (const float*)d_in[5];
  const float* proj_b = (const float*)d_in[6];
  float* out = (float*)d_out;
  const int ncu = in_sizes[2];

  // workspace layout (~53.4 MB total)
  char* ws = (char*)d_ws;
  u16* Abf = (u16*)ws; ws += (size_t)SEQ*DIM*2;       // hidden bf16
  u16* Wq  = (u16*)ws; ws += (size_t)3*DIM*DIM*2;     // qkv_w bf16
  u16* Wp  = (u16*)ws; ws += (size_t)DIM*DIM*2;       // proj_w bf16
  u16* qws = (u16*)ws; ws += (size_t)NH*SEQ*HD*2;     // q [h][s][80]
  u16* kws = (u16*)ws; ws += (size_t)NH*SEQ*HD*2;     // k [h][s][80]
  u16* vTw = (u16*)ws; ws += (size_t)NH*SEQ*HD*2;     // v^T [h][80][s]
  u16* ows = (u16*)ws; ws += (size_t)SEQ*DIM*2;       // attn out [s][1280]
  float2* tab = (float2*)ws; ws += (size_t)NTAB*8;    // rope cos/sin table

  cvt_kernel<<<(N4_A+N4_B+N4_C+NTAB+255)/256, 256, 0, stream>>>(
      hidden, Abf, qkv_w, Wq, proj_w, Wp, rope, tab);

  gemm_kernel<<<dim3(3*DIM/128, SEQ/128), 256, 0, stream>>>(
      Abf, Wq, qkv_b, qws, kws, vTw, SEQ, 3*DIM, DIM);

  rope_apply_kernel<<<(NH*SEQ*5 + 255)/256, 256, 0, stream>>>(qws, kws, tab);

  attn_kernel<<<NH*(SEQ/32), 128, 0, stream>>>(qws, kws, vTw, cu, ncu, ows);

  gemm1_kernel<<<dim3(DIM/64, SEQ/128), 128, 0, stream>>>(
      ows, Wp, proj_b, out, SEQ, DIM, DIM);
}

// Round 17
// 147.703 us; speedup vs baseline: 1.0932x; 1.0401x over previous
//
#include <hip/hip_runtime.h>
#include <cstdint>
#include <cstddef>

#define SEQ 3072
#define DIM 1280
#define NH 16
#define HD 80

typedef __attribute__((ext_vector_type(8))) short s16x8;   // 8 x bf16 (4 VGPR)
typedef __attribute__((ext_vector_type(4))) float f32x4;   // MFMA accumulator
typedef unsigned short u16;
typedef unsigned int u32;
typedef unsigned long long u64;

__device__ __forceinline__ u16 f2bf(float f) {
  u32 u = __builtin_bit_cast(u32, f);
  u32 r = (u + 0x7FFFu + ((u >> 16) & 1u)) >> 16;   // RNE
  return (u16)r;
}
__device__ __forceinline__ float bf2f(u16 b) {
  u32 u = ((u32)b) << 16;
  return __builtin_bit_cast(float, u);
}
__device__ __forceinline__ u32 cvtpk_bf16(float lo, float hi) {
  u32 r;
  asm("v_cvt_pk_bf16_f32 %0, %1, %2" : "=v"(r) : "v"(lo), "v"(hi));
  return r;
}
__device__ __forceinline__ void gload16(const u16* g, u16* lds) {
  __builtin_amdgcn_global_load_lds((const __attribute__((address_space(1))) void*)g,
                                   (__attribute__((address_space(3))) void*)lds,
                                   16, 0, 0);
}

// ---------------- fused f32->bf16 convert (hidden, qkv_w, proj_w) + rope table ----
#define N4_A (SEQ*DIM/4)
#define N4_B (3*DIM*DIM/4)
#define N4_C (DIM*DIM/4)
#define NTAB (SEQ*(HD/2))
__global__ void cvt_kernel(const float* __restrict__ sa, u16* __restrict__ da,
                           const float* __restrict__ sb, u16* __restrict__ db,
                           const float* __restrict__ sc, u16* __restrict__ dc,
                           const float* __restrict__ freqs, float2* __restrict__ tab) {
  int i = blockIdx.x * blockDim.x + threadIdx.x;
  if (i < N4_A + N4_B + N4_C) {
    const float* s; u16* d; int j;
    if (i < N4_A)           { s = sa; d = da; j = i; }
    else if (i < N4_A+N4_B) { s = sb; d = db; j = i - N4_A; }
    else                    { s = sc; d = dc; j = i - N4_A - N4_B; }
    float4 v = ((const float4*)s)[j];
    ushort4 o;
    o.x = f2bf(v.x); o.y = f2bf(v.y); o.z = f2bf(v.z); o.w = f2bf(v.w);
    ((ushort4*)d)[j] = o;
  } else {
    int j = i - (N4_A + N4_B + N4_C);
    if (j < NTAB) {
      float f = freqs[j];
      tab[j] = make_float2(cosf(f), sinf(f));
    }
  }
}

// ---------------- qkv GEMM: 128x128, BK=32, double-buffered LDS (R7/R13 best) ----
// Stage t+1 into buf^1 BEFORE compute of buf, ONE __syncthreads per K-step.
// (R8/R16 lesson: counted vmcnt + raw barriers regress with or without
// sched_barrier pins — the compiler's own schedule around __syncthreads wins.)
__global__ __launch_bounds__(256)
void gemm_kernel(const u16* __restrict__ A, const u16* __restrict__ B,
                 const float* __restrict__ bias,
                 u16* __restrict__ qws, u16* __restrict__ kws, u16* __restrict__ vT,
                 int M, int N, int K)
{
  constexpr int BM = 128, BN = 128, BK = 32;
  __shared__ __align__(16) u16 As[2][BM*BK];
  __shared__ __align__(16) u16 Bs[2][BN*BK];
  const int m0 = blockIdx.y * BM, n0 = blockIdx.x * BN;
  const int tid = threadIdx.x;
  const int lane = tid & 63, wave = tid >> 6;
  const int wr = wave >> 1, wc = wave & 1;     // 2x2 waves, each 64x64
  const int lr = lane & 15, lg = lane >> 4;

  const int c0 = tid, c1 = 256 + tid;
  const int r0 = c0 >> 2, cc0 = c0 & 3;
  const int r1 = c1 >> 2, cc1 = c1 & 3;
  const int wb0 = (tid & ~63), wb1 = 256 + (tid & ~63);

  f32x4 acc[4][4];
  #pragma unroll
  for (int i = 0; i < 4; ++i)
    #pragma unroll
    for (int j = 0; j < 4; ++j) acc[i][j] = (f32x4)0.0f;

  const int NT = K / BK;

  gload16(A + (size_t)(m0 + r0)*K + cc0*8, &As[0][0] + wb0*8);
  gload16(B + (size_t)(n0 + r0)*K + cc0*8, &Bs[0][0] + wb0*8);
  gload16(A + (size_t)(m0 + r1)*K + cc1*8, &As[0][0] + wb1*8);
  gload16(B + (size_t)(n0 + r1)*K + cc1*8, &Bs[0][0] + wb1*8);
  __syncthreads();

  int cur = 0;
  for (int t = 0; t < NT; ++t) {
    if (t + 1 < NT) {
      const int k0 = (t + 1) * BK;
      const int nxt = cur ^ 1;
      gload16(A + (size_t)(m0 + r0)*K + k0 + cc0*8, &As[nxt][0] + wb0*8);
      gload16(B + (size_t)(n0 + r0)*K + k0 + cc0*8, &Bs[nxt][0] + wb0*8);
      gload16(A + (size_t)(m0 + r1)*K + k0 + cc1*8, &As[nxt][0] + wb1*8);
      gload16(B + (size_t)(n0 + r1)*K + k0 + cc1*8, &Bs[nxt][0] + wb1*8);
    }
    s16x8 af[4], bf[4];
    #pragma unroll
    for (int i = 0; i < 4; ++i) {
      af[i] = *(const s16x8*)&As[cur][(wr*64 + i*16 + lr)*BK + lg*8];
      bf[i] = *(const s16x8*)&Bs[cur][(wc*64 + i*16 + lr)*BK + lg*8];
    }
    #pragma unroll
    for (int mi = 0; mi < 4; ++mi)
      #pragma unroll
      for (int ni = 0; ni < 4; ++ni)
        acc[mi][ni] = __builtin_amdgcn_mfma_f32_16x16x32_bf16(af[mi], bf[ni], acc[mi][ni], 0, 0, 0);
    __syncthreads();
    cur ^= 1;
  }

  // epilogue: D layout col = lane&15, row = (lane>>4)*4 + reg; scatter q,k,v^T
  #pragma unroll
  for (int ni = 0; ni < 4; ++ni) {
    const int n = n0 + wc*64 + ni*16 + lr;
    const float bv = bias[n];
    const int which = n / DIM;
    const int hd = n - which*DIM;
    const int h = hd / HD;
    const int d = hd - h*HD;
    #pragma unroll
    for (int mi = 0; mi < 4; ++mi) {
      const int mb = m0 + wr*64 + mi*16 + lg*4;
      #pragma unroll
      for (int j = 0; j < 4; ++j) {
        const u16 b = f2bf(acc[mi][ni][j] + bv);
        const int m = mb + j;
        if (which == 0)      qws[((size_t)h*SEQ + m)*HD + d] = b;
        else if (which == 1) kws[((size_t)h*SEQ + m)*HD + d] = b;
        else                 vT [((size_t)h*HD + d)*SEQ + m] = b;
      }
    }
  }
}

// ---------------- proj GEMM: 128x64 tile, 2 waves, dbuf (grid 480) ----
__global__ __launch_bounds__(128)
void gemm1_kernel(const u16* __restrict__ A, const u16* __restrict__ B,
                  const float* __restrict__ bias, float* __restrict__ fout,
                  int M, int N, int K)
{
  constexpr int BM = 128, BN = 64, BK = 32;
  __shared__ __align__(16) u16 As[2][BM*BK];
  __shared__ __align__(16) u16 Bs[2][BN*BK];
  const int m0 = blockIdx.y * BM, n0 = blockIdx.x * BN;
  const int tid = threadIdx.x;
  const int lane = tid & 63, wave = tid >> 6;   // 2 waves stacked on M
  const int lr = lane & 15, lg = lane >> 4;

  int rA[4], cA[4], wbA[4];
  #pragma unroll
  for (int i = 0; i < 4; ++i) {
    const int c = i*128 + tid;
    rA[i] = c >> 2; cA[i] = c & 3;
    wbA[i] = i*128 + (tid & ~63);
  }
  int rB[2], cB[2], wbB[2];
  #pragma unroll
  for (int i = 0; i < 2; ++i) {
    const int c = i*128 + tid;
    rB[i] = c >> 2; cB[i] = c & 3;
    wbB[i] = i*128 + (tid & ~63);
  }

  f32x4 acc[4][4];
  #pragma unroll
  for (int i = 0; i < 4; ++i)
    #pragma unroll
    for (int j = 0; j < 4; ++j) acc[i][j] = (f32x4)0.0f;

  const int NT = K / BK;

  auto stage = [&](int t, int buf) {
    const int k0 = t * BK;
    #pragma unroll
    for (int i = 0; i < 4; ++i)
      gload16(A + (size_t)(m0 + rA[i])*K + k0 + cA[i]*8, &As[buf][0] + wbA[i]*8);
    #pragma unroll
    for (int i = 0; i < 2; ++i)
      gload16(B + (size_t)(n0 + rB[i])*K + k0 + cB[i]*8, &Bs[buf][0] + wbB[i]*8);
  };

  stage(0, 0);
  __syncthreads();

  int cur = 0;
  for (int t = 0; t < NT; ++t) {
    if (t + 1 < NT) stage(t + 1, cur ^ 1);
    s16x8 af[4], bf[4];
    #pragma unroll
    for (int i = 0; i < 4; ++i) {
      af[i] = *(const s16x8*)&As[cur][(wave*64 + i*16 + lr)*BK + lg*8];
      bf[i] = *(const s16x8*)&Bs[cur][(i*16 + lr)*BK + lg*8];
    }
    #pragma unroll
    for (int mi = 0; mi < 4; ++mi)
      #pragma unroll
      for (int ni = 0; ni < 4; ++ni)
        acc[mi][ni] = __builtin_amdgcn_mfma_f32_16x16x32_bf16(af[mi], bf[ni], acc[mi][ni], 0, 0, 0);
    __syncthreads();
    cur ^= 1;
  }

  #pragma unroll
  for (int ni = 0; ni < 4; ++ni) {
    const int n = n0 + ni*16 + lr;
    const float bv = bias[n];
    #pragma unroll
    for (int mi = 0; mi < 4; ++mi) {
      const int mb = m0 + wave*64 + mi*16 + lg*4;
      #pragma unroll
      for (int j = 0; j < 4; ++j)
        fout[(size_t)(mb + j)*N + n] = acc[mi][ni][j] + bv;
    }
  }
}

// ---------------- RoPE apply (vectorized; tab precomputed in cvt) ----------------
__global__ void rope_apply_kernel(u16* __restrict__ q, u16* __restrict__ k,
                                  const float2* __restrict__ tab) {
  int idx = blockIdx.x*blockDim.x + threadIdx.x;   // NH*SEQ*5
  if (idx >= NH*SEQ*5) return;
  const int c = idx % 5;
  const int s = (idx / 5) % SEQ;
  const int h = idx / (5*SEQ);
  const int d0 = c*8;
  const float2* tp = tab + s*(HD/2) + d0;
  float cs[8], sn[8];
  #pragma unroll
  for (int j = 0; j < 8; ++j) { float2 f = tp[j]; cs[j] = f.x; sn[j] = f.y; }
  const size_t base = ((size_t)h*SEQ + s)*HD;
  {
    s16x8 x = *(const s16x8*)(q + base + d0);
    s16x8 y = *(const s16x8*)(q + base + (HD/2) + d0);
    s16x8 nx, ny;
    #pragma unroll
    for (int j = 0; j < 8; ++j) {
      float xv = bf2f((u16)x[j]), yv = bf2f((u16)y[j]);
      nx[j] = (short)f2bf(xv*cs[j] - yv*sn[j]);
      ny[j] = (short)f2bf(yv*cs[j] + xv*sn[j]);
    }
    *(s16x8*)(q + base + d0) = nx;
    *(s16x8*)(q + base + (HD/2) + d0) = ny;
  }
  {
    s16x8 x = *(const s16x8*)(k + base + d0);
    s16x8 y = *(const s16x8*)(k + base + (HD/2) + d0);
    s16x8 nx, ny;
    #pragma unroll
    for (int j = 0; j < 8; ++j) {
      float xv = bf2f((u16)x[j]), yv = bf2f((u16)y[j]);
      nx[j] = (short)f2bf(xv*cs[j] - yv*sn[j]);
      ny[j] = (short)f2bf(yv*cs[j] + xv*sn[j]);
    }
    *(s16x8*)(k + base + d0) = nx;
    *(s16x8*)(k + base + (HD/2) + d0) = ny;
  }
}

// ---------------- attention: split-K x2 (2 indep waves / 32 q rows), end-merge ----
struct AttnState {
  float m_run[2];
  float lp[2];
  f32x4 oacc[2][5];
};

__device__ __forceinline__ void load_kv(const u16* __restrict__ kbase,
                                        const u16* __restrict__ vbase,
                                        int lr, int lg, int kc,
                                        s16x8 (&KF)[2][3], s16x8 (&VF)[5]) {
  int kcl = kc; if (kcl > SEQ-32) kcl = SEQ-32;
  #pragma unroll
  for (int kt = 0; kt < 2; ++kt)
    #pragma unroll
    for (int s = 0; s < 3; ++s) {
      const int d0 = s*32 + lg*8;
      if (d0 < HD) KF[kt][s] = *(const s16x8*)(kbase + (size_t)(kcl + kt*16 + lr)*HD + d0);
      else         KF[kt][s] = (s16x8)(short)0;
    }
  #pragma unroll
  for (int dt = 0; dt < 5; ++dt)
    VF[dt] = *(const s16x8*)(vbase + (size_t)(dt*16 + lr)*SEQ + kcl + lg*8);
}

__device__ __forceinline__ void compute_chunk(int kc, const s16x8 (&KF)[2][3], const s16x8 (&VF)[5],
                                              const s16x8 (&qf)[2][3], AttnState& st,
                                              u16 (&P_lds)[2][16][32],
                                              int lr, int lg, int swz,
                                              int rs0, int re0, int rs1, int re1) {
  const float NEG = -__builtin_inff();
  const float DTH = 8.0f;
  const float kscale = 0.11180339887498949f * 1.44269504088896341f; // 1/sqrt(80)*log2(e)

  f32x4 sacc[2][2];
  #pragma unroll
  for (int qs = 0; qs < 2; ++qs)
    #pragma unroll
    for (int kt = 0; kt < 2; ++kt) sacc[qs][kt] = (f32x4)0.0f;
  #pragma unroll
  for (int kt = 0; kt < 2; ++kt)
    #pragma unroll
    for (int s = 0; s < 3; ++s) {
      sacc[0][kt] = __builtin_amdgcn_mfma_f32_16x16x32_bf16(KF[kt][s], qf[0][s], sacc[0][kt], 0, 0, 0);
      sacc[1][kt] = __builtin_amdgcn_mfma_f32_16x16x32_bf16(KF[kt][s], qf[1][s], sacc[1][kt], 0, 0, 0);
    }

  float sv[2][8];
  #pragma unroll
  for (int qs = 0; qs < 2; ++qs)
    #pragma unroll
    for (int kt = 0; kt < 2; ++kt)
      #pragma unroll
      for (int j = 0; j < 4; ++j)
        sv[qs][kt*4+j] = sacc[qs][kt][j] * kscale;

  const bool full = __all((kc >= rs0) && (kc+32 <= re0) && (kc >= rs1) && (kc+32 <= re1));
  if (!full) {
    #pragma unroll
    for (int qs = 0; qs < 2; ++qs) {
      const int rsq = qs ? rs1 : rs0, req = qs ? re1 : re0;
      #pragma unroll
      for (int kt = 0; kt < 2; ++kt)
        #pragma unroll
        for (int j = 0; j < 4; ++j) {
          const int key = kc + kt*16 + lg*4 + j;
          if (key < rsq || key >= req) sv[qs][kt*4+j] = NEG;
        }
    }
  }

  float pc[2];
  #pragma unroll
  for (int qs = 0; qs < 2; ++qs) {
    float c = sv[qs][0];
    #pragma unroll
    for (int i = 1; i < 8; ++i) c = fmaxf(c, sv[qs][i]);
    pc[qs] = c;
  }

  const bool nore = __all((pc[0] - st.m_run[0] <= DTH) && (pc[1] - st.m_run[1] <= DTH));
  u32 pk[2][4];
  if (nore) {
    #pragma unroll
    for (int qs = 0; qs < 2; ++qs) {
      const float m = st.m_run[qs];
      float ps = 0.0f;
      #pragma unroll
      for (int i2 = 0; i2 < 4; ++i2) {
        float pa = __builtin_amdgcn_exp2f(sv[qs][2*i2]   - m);
        float pb = __builtin_amdgcn_exp2f(sv[qs][2*i2+1] - m);
        ps += pa + pb;
        pk[qs][i2] = cvtpk_bf16(pa, pb);
      }
      st.lp[qs] += ps;
    }
  } else {
    #pragma unroll
    for (int qs = 0; qs < 2; ++qs) {
      float c = pc[qs];
      c = fmaxf(c, __shfl_xor(c, 16, 64));
      c = fmaxf(c, __shfl_xor(c, 32, 64));
      const float mn = fmaxf(st.m_run[qs], c);
      const float fs = (mn == st.m_run[qs]) ? 1.0f : __builtin_amdgcn_exp2f(st.m_run[qs] - mn);
      float ps = 0.0f;
      #pragma unroll
      for (int i2 = 0; i2 < 4; ++i2) {
        float a0 = sv[qs][2*i2], a1 = sv[qs][2*i2+1];
        float pa = (a0 == NEG) ? 0.0f : __builtin_amdgcn_exp2f(a0 - mn);
        float pb = (a1 == NEG) ? 0.0f : __builtin_amdgcn_exp2f(a1 - mn);
        ps += pa + pb;
        pk[qs][i2] = cvtpk_bf16(pa, pb);
      }
      st.lp[qs] = st.lp[qs] * fs + ps;
      st.m_run[qs] = mn;
      float fr[4];
      #pragma unroll
      for (int j = 0; j < 4; ++j)
        fr[j] = __builtin_bit_cast(float,
                  __builtin_amdgcn_ds_bpermute((lg*4 + j)*4, __builtin_bit_cast(int, fs)));
      #pragma unroll
      for (int dt = 0; dt < 5; ++dt)
        #pragma unroll
        for (int j = 0; j < 4; ++j) st.oacc[qs][dt][j] *= fr[j];
    }
  }

  #pragma unroll
  for (int qs = 0; qs < 2; ++qs) {
    u64 w0 = (u64)pk[qs][0] | ((u64)pk[qs][1] << 32);
    u64 w1 = (u64)pk[qs][2] | ((u64)pk[qs][3] << 32);
    u64* P64 = (u64*)&P_lds[qs][0][0];
    P64[lr*8 + ( lg      ^ (swz<<1))] = w0;
    P64[lr*8 + ((4 + lg) ^ (swz<<1))] = w1;
  }
  s16x8 pa0 = *(const s16x8*)&P_lds[0][lr][(lg ^ swz) * 8];
  s16x8 pa1 = *(const s16x8*)&P_lds[1][lr][(lg ^ swz) * 8];

  #pragma unroll
  for (int dt = 0; dt < 5; ++dt) {
    st.oacc[0][dt] = __builtin_amdgcn_mfma_f32_16x16x32_bf16(pa0, VF[dt], st.oacc[0][dt], 0, 0, 0);
    st.oacc[1][dt] = __builtin_amdgcn_mfma_f32_16x16x32_bf16(pa1, VF[dt], st.oacc[1][dt], 0, 0, 0);
  }
}

__global__ __launch_bounds__(128)
void attn_kernel(const u16* __restrict__ qws, const u16* __restrict__ kws,
                 const u16* __restrict__ vT, const int* __restrict__ cu, int ncu,
                 u16* __restrict__ ows /* [SEQ][DIM] bf16 */)
{
  __shared__ __align__(16) u16 P_lds[2][2][16][32];   // [wave][qs][q][32 keys]
  __shared__ float mstat[2][2][16];                   // [wave][qs][row(lr)]
  __shared__ float lstat[2][2][16];
  __shared__ float O_lds[32][84];                     // wave1's scaled O (+4 pad)
  const int h = blockIdx.x & 15;         // head pinned by bid%8 == h%8
  const int t = blockIdx.x >> 4;
  const int tid = threadIdx.x;
  const int w = tid >> 6;
  const int lane = tid & 63;
  const int lr = lane & 15, lg = lane >> 4;
  const int q0 = t*32;
  const float NEG = -__builtin_inff();

  int rs0 = cu[0], re0 = cu[1], rs1 = cu[0], re1 = cu[1];
  int ts = cu[0], te = cu[1];
  {
    const int qa = q0 + lr, qb = q0 + 16 + lr;
    for (int i = 1; i < ncu-1; ++i) {
      int lo = cu[i], hi = cu[i+1];
      if (qa    >= lo) { rs0 = lo; re0 = hi; }
      if (qb    >= lo) { rs1 = lo; re1 = hi; }
      if (q0    >= lo) { ts = lo; }
      if (q0+31 >= lo) { te = hi; }
    }
  }

  const u16* kbase = kws + (size_t)h*SEQ*HD;
  const u16* vbase = vT  + (size_t)h*HD*SEQ;

  s16x8 qf[2][3];
  #pragma unroll
  for (int qs = 0; qs < 2; ++qs)
    #pragma unroll
    for (int s = 0; s < 3; ++s) {
      int d0 = s*32 + lg*8;
      if (d0 < HD) qf[qs][s] = *(const s16x8*)(qws + ((size_t)h*SEQ + q0 + qs*16 + lr)*HD + d0);
      else         qf[qs][s] = (s16x8)(short)0;
    }

  AttnState st;
  st.m_run[0] = NEG; st.m_run[1] = NEG;
  st.lp[0] = 0.0f;   st.lp[1] = 0.0f;
  #pragma unroll
  for (int qs = 0; qs < 2; ++qs)
    #pragma unroll
    for (int dt = 0; dt < 5; ++dt) st.oacc[qs][dt] = (f32x4)0.0f;

  const int swz = (lr >> 1) & 3;

  const int kc0 = ts & ~31;
  const int nch = (te - kc0 + 31) >> 5;
  const int n_w = (nch - w + 1) >> 1;    // chunks at indices w, w+2, ...

  s16x8 kfA[2][3], vfA[5], kfB[2][3], vfB[5];
  const int kcw0 = kc0 + w*32;
  if (n_w > 0) load_kv(kbase, vbase, lr, lg, kcw0, kfA, vfA);

  int kc = kcw0, i = 0;
  for (; i + 2 <= n_w; i += 2) {
    load_kv(kbase, vbase, lr, lg, kc+64,  kfB, vfB);    // prefetch n+1 (stride 64)
    compute_chunk(kc, kfA, vfA, qf, st, P_lds[w], lr, lg, swz, rs0, re0, rs1, re1);
    load_kv(kbase, vbase, lr, lg, kc+128, kfA, vfA);    // prefetch n+2 (clamped)
    compute_chunk(kc+64, kfB, vfB, qf, st, P_lds[w], lr, lg, swz, rs0, re0, rs1, re1);
    kc += 128;
  }
  if (i < n_w)
    compute_chunk(kc, kfA, vfA, qf, st, P_lds[w], lr, lg, swz, rs0, re0, rs1, re1);

  // ---- finalize per-wave l; publish (m, l) per row ----
  #pragma unroll
  for (int qs = 0; qs < 2; ++qs) {
    st.lp[qs] += __shfl_xor(st.lp[qs], 16, 64);
    st.lp[qs] += __shfl_xor(st.lp[qs], 32, 64);
  }
  if (lg == 0) {
    mstat[w][0][lr] = st.m_run[0]; lstat[w][0][lr] = st.lp[0];
    mstat[w][1][lr] = st.m_run[1]; lstat[w][1][lr] = st.lp[1];
  }
  __syncthreads();

  // ---- per-lane merge factors for own rows r = lg*4+j ----
  float fac[2][4], lin[2][4];
  #pragma unroll
  for (int qs = 0; qs < 2; ++qs)
    #pragma unroll
    for (int j = 0; j < 4; ++j) {
      const int r = lg*4 + j;
      const float m0 = mstat[0][qs][r], m1 = mstat[1][qs][r];
      const float mst = fmaxf(m0, m1);
      float lst = 0.0f;
      if (m0 != NEG) lst += lstat[0][qs][r] * __builtin_amdgcn_exp2f(m0 - mst);
      if (m1 != NEG) lst += lstat[1][qs][r] * __builtin_amdgcn_exp2f(m1 - mst);
      const float mw = w ? m1 : m0;
      fac[qs][j] = (mw == NEG) ? 0.0f : __builtin_amdgcn_exp2f(mw - mst);
      lin[qs][j] = 1.0f / lst;
    }

  // ---- wave 1 deposits scaled O; wave 0 combines, normalizes, stores ----
  if (w == 1) {
    #pragma unroll
    for (int qs = 0; qs < 2; ++qs)
      #pragma unroll
      for (int dt = 0; dt < 5; ++dt)
        #pragma unroll
        for (int j = 0; j < 4; ++j)
          O_lds[qs*16 + lg*4 + j][dt*16 + lr] = st.oacc[qs][dt][j] * fac[qs][j];
  }
  __syncthreads();
  if (w == 0) {
    #pragma unroll
    for (int qs = 0; qs < 2; ++qs)
      #pragma unroll
      for (int dt = 0; dt < 5; ++dt)
        #pragma unroll
        for (int j = 0; j < 4; ++j) {
          float v = (st.oacc[qs][dt][j] * fac[qs][j] + O_lds[qs*16 + lg*4 + j][dt*16 + lr])
                    * lin[qs][j];
          ows[(size_t)(q0 + qs*16 + lg*4 + j)*DIM + h*HD + dt*16 + lr] = f2bf(v);
        }
  }
}

// ---------------- launch ----------------
extern "C" void kernel_launch(void* const* d_in, const int* in_sizes, int n_in,
                              void* d_out, int out_size, void* d_ws, size_t ws_size,
                              hipStream_t stream) {
  const float* hidden = (const float*)d_in[0];
  const float* rope   = (const float*)d_in[1];
  const int*   cu     = (const int*)d_in[2];
  const float* qkv_w  = (const float*)d_in[3];
  const float* qkv_b  = (const float*)d_in[4];
  const float* proj_w = (const float*)d_in[5];
  const float* proj_b = (const float*)d_in[6];
  float* out = (float*)d_out;
  const int ncu = in_sizes[2];

  // workspace layout (~53.4 MB total)
  char* ws = (char*)d_ws;
  u16* Abf = (u16*)ws; ws += (size_t)SEQ*DIM*2;       // hidden bf16
  u16* Wq  = (u16*)ws; ws += (size_t)3*DIM*DIM*2;     // qkv_w bf16
  u16* Wp  = (u16*)ws; ws += (size_t)DIM*DIM*2;       // proj_w bf16
  u16* qws = (u16*)ws; ws += (size_t)NH*SEQ*HD*2;     // q [h][s][80]
  u16* kws = (u16*)ws; ws += (size_t)NH*SEQ*HD*2;     // k [h][s][80]
  u16* vTw = (u16*)ws; ws += (size_t)NH*SEQ*HD*2;     // v^T [h][80][s]
  u16* ows = (u16*)ws; ws += (size_t)SEQ*DIM*2;       // attn out [s][1280]
  float2* tab = (float2*)ws; ws += (size_t)NTAB*8;    // rope cos/sin table

  cvt_kernel<<<(N4_A+N4_B+N4_C+NTAB+255)/256, 256, 0, stream>>>(
      hidden, Abf, qkv_w, Wq, proj_w, Wp, rope, tab);

  gemm_kernel<<<dim3(3*DIM/128, SEQ/128), 256, 0, stream>>>(
      Abf, Wq, qkv_b, qws, kws, vTw, SEQ, 3*DIM, DIM);

  rope_apply_kernel<<<(NH*SEQ*5 + 255)/256, 256, 0, stream>>>(qws, kws, tab);

  attn_kernel<<<NH*(SEQ/32), 128, 0, stream>>>(qws, kws, vTw, cu, ncu, ows);

  gemm1_kernel<<<dim3(DIM/64, SEQ/128), 128, 0, stream>>>(
      ows, Wp, proj_b, out, SEQ, DIM, DIM);
}